// Round 4
// baseline (464.157 us; speedup 1.0000x reference)
//
#include <hip/hip_runtime.h>
#include <stdint.h>

typedef float f32x4 __attribute__((ext_vector_type(4)));
typedef __bf16 bf16x8 __attribute__((ext_vector_type(8)));
typedef unsigned short u16x8 __attribute__((ext_vector_type(8)));

__device__ __forceinline__ unsigned short f2bf(float f) {
  union { float f; unsigned u; } x; x.f = f;
  unsigned r = x.u + 0x7fffu + ((x.u >> 16) & 1u);
  return (unsigned short)(r >> 16);
}
__device__ __forceinline__ float bf2f(unsigned short u) {
  union { unsigned u; float f; } x; x.u = ((unsigned)u) << 16;
  return x.f;
}
__device__ __forceinline__ void async_copy16(void* lds, const void* g) {
  __builtin_amdgcn_global_load_lds(
      (const unsigned int __attribute__((address_space(1)))*)g,
      (unsigned int __attribute__((address_space(3)))*)lds, 16, 0, 0);
}
__device__ __forceinline__ f32x4 mfma16(bf16x8 a, bf16x8 b, f32x4 c) {
  return __builtin_amdgcn_mfma_f32_16x16x32_bf16(a, b, c, 0, 0, 0);
}

// ---------------- fp32 -> bf16 convert ----------------
__global__ __launch_bounds__(256) void cvt_f32_bf16(
    const float* __restrict__ in, unsigned short* __restrict__ out, int n8) {
  int stride = gridDim.x * blockDim.x;
  for (int i = blockIdx.x * blockDim.x + threadIdx.x; i < n8; i += stride) {
    const float4* p = (const float4*)in + (size_t)i * 2;
    float4 a = p[0], b = p[1];
    u16x8 o;
    o[0] = f2bf(a.x); o[1] = f2bf(a.y); o[2] = f2bf(a.z); o[3] = f2bf(a.w);
    o[4] = f2bf(b.x); o[5] = f2bf(b.y); o[6] = f2bf(b.z); o[7] = f2bf(b.w);
    *((u16x8*)out + i) = o;
  }
}

// ---------------- RoPE cos/sin table: [2048][64] float2 (cos,sin) ----------------
__global__ __launch_bounds__(256) void rope_table(float2* __restrict__ cs) {
  int idx = blockIdx.x * 256 + threadIdx.x;   // 2048*64 = 131072
  if (idx >= 2048 * 64) return;
  int t = idx >> 6, j = idx & 63;
  float inv = expf(-0.14391156516026f * (float)j);
  float ang = (float)t * inv;
  cs[idx] = make_float2(cosf(ang), sinf(ang));
}

// ---------------- GEMM v2: C[M,N] = A[M,K] * Bt[N,K]^T ----------------
// BM=128, BN=256, BK=32; 512 thr = 8 waves (2M x 4N), 64x64 out per wave.
// Triple-buffered LDS (72 KB), counted s_waitcnt vmcnt(3) (loads for tile t
// issued at iter t-2, hidden under a full tile of compute). Swizzle:
// slot ^= (row&3) ^ ((row>>2)&3)  -> 2 lanes per 16B slot-class (free).
template <bool OUT_F32>
__global__ __launch_bounds__(512, 2) void gemm_bt2(
    const unsigned short* __restrict__ A, const unsigned short* __restrict__ Bt,
    void* __restrict__ Cout, int M, int N, int K) {
  __shared__ unsigned short sA[3][128 * 32];
  __shared__ unsigned short sB[3][256 * 32];
  const int tid = threadIdx.x;
  const int w = tid >> 6, l = tid & 63;
  const int wm = w >> 2, wn = w & 3;
  const int g = l >> 4, lr = l & 15;
  const int m0 = blockIdx.y * 128, n0 = blockIdx.x * 256;

  f32x4 acc[4][4];
#pragma unroll
  for (int i = 0; i < 4; ++i)
#pragma unroll
    for (int j = 0; j < 4; ++j) acc[i][j] = f32x4{0.f, 0.f, 0.f, 0.f};

  auto stage = [&](int buf, int kt) {
    const int k0 = kt * 32;
    {
      int unit = w * 64 + l;                  // A: 128 rows x 4 slots
      int row = unit >> 2, s = unit & 3;
      int sg = s ^ (row & 3) ^ ((row >> 2) & 3);
      async_copy16(&sA[buf][w * 512],
                   A + (size_t)(m0 + row) * K + k0 + sg * 8);
    }
#pragma unroll
    for (int j = 0; j < 2; ++j) {
      int unit = j * 512 + w * 64 + l;        // B: 256 rows x 4 slots
      int row = unit >> 2, s = unit & 3;
      int sg = s ^ (row & 3) ^ ((row >> 2) & 3);
      async_copy16(&sB[buf][(j * 8 + w) * 512],
                   Bt + (size_t)(n0 + row) * K + k0 + sg * 8);
    }
  };

  const int NK = K / 32;
  stage(0, 0);
  stage(1, 1);
  for (int kt = 0; kt < NK; ++kt) {
    const int cur = kt % 3;
    if (kt + 1 < NK) asm volatile("s_waitcnt vmcnt(3)" ::: "memory");
    else             asm volatile("s_waitcnt vmcnt(0)" ::: "memory");
    __syncthreads();                       // tile kt visible to all waves
    if (kt + 2 < NK) stage((kt + 2) % 3, kt + 2);  // fly during compute

    bf16x8 af[4], bq[4];
#pragma unroll
    for (int mi = 0; mi < 4; ++mi) {
      int row = wm * 64 + mi * 16 + lr;
      int sl = g ^ (row & 3) ^ ((row >> 2) & 3);
      af[mi] = *(const bf16x8*)&sA[cur][row * 32 + sl * 8];
    }
#pragma unroll
    for (int ni = 0; ni < 4; ++ni) {
      int row = wn * 64 + ni * 16 + lr;
      int sl = g ^ (row & 3) ^ ((row >> 2) & 3);
      bq[ni] = *(const bf16x8*)&sB[cur][row * 32 + sl * 8];
    }
    __builtin_amdgcn_s_setprio(1);
#pragma unroll
    for (int mi = 0; mi < 4; ++mi)
#pragma unroll
      for (int ni = 0; ni < 4; ++ni)
        acc[mi][ni] = mfma16(af[mi], bq[ni], acc[mi][ni]);
    __builtin_amdgcn_s_setprio(0);
    __syncthreads();                       // reads of cur done before restage
  }

#pragma unroll
  for (int mi = 0; mi < 4; ++mi)
#pragma unroll
    for (int ni = 0; ni < 4; ++ni) {
      int col = n0 + wn * 64 + ni * 16 + lr;
#pragma unroll
      for (int jr = 0; jr < 4; ++jr) {
        int row = m0 + wm * 64 + mi * 16 + g * 4 + jr;
        float v = acc[mi][ni][jr];
        if (OUT_F32)
          ((float*)Cout)[(size_t)row * N + col] = v;
        else
          ((unsigned short*)Cout)[(size_t)row * N + col] = f2bf(v);
      }
    }
}

// ---------------- RoPE + scatter: qkv[4096][6144] -> Q,K [bh][T][128], Vt [bh][128][T] ----------------
__global__ __launch_bounds__(256) void prep_rope(
    const unsigned short* __restrict__ qkv, const float2* __restrict__ cs,
    unsigned short* __restrict__ Q, unsigned short* __restrict__ K,
    unsigned short* __restrict__ Vt) {
  const int tt = blockIdx.x, h = blockIdx.y, b = blockIdx.z;
  const int t0 = tt * 64;
  const int tid = threadIdx.x;
  __shared__ unsigned short vt[64][130];   // +2 pad: conflict-free column reads

#pragma unroll 4
  for (int i = 0; i < 32; ++i) {
    int lin = i * 256 + tid;             // 64 rows x 128 dims
    int r = lin >> 7, j = lin & 127;
    int t = t0 + r;
    int jj = j & 63;
    size_t rowbase = ((size_t)(b * 2048 + t)) * 6144 + h * 128;
    float2 c_s = cs[t * 64 + jj];
    float q1 = bf2f(qkv[rowbase + 2 * jj]);
    float q2 = bf2f(qkv[rowbase + 2 * jj + 1]);
    float k1 = bf2f(qkv[rowbase + 2048 + 2 * jj]);
    float k2 = bf2f(qkv[rowbase + 2048 + 2 * jj + 1]);
    float qo = (j < 64) ? (q1 * c_s.x - q2 * c_s.y) : (q1 * c_s.y + q2 * c_s.x);
    float ko = (j < 64) ? (k1 * c_s.x - k2 * c_s.y) : (k1 * c_s.y + k2 * c_s.x);
    size_t obase = ((size_t)((b * 16 + h) * 2048 + t)) * 128 + j;
    Q[obase] = f2bf(qo);
    K[obase] = f2bf(ko);
    vt[r][j] = qkv[rowbase + 4096 + j];
  }
  __syncthreads();
  size_t vbase = ((size_t)((b * 16 + h) * 128)) * 2048 + t0;
#pragma unroll 4
  for (int i = 0; i < 32; ++i) {
    int lin = i * 256 + tid;
    int d = lin >> 6, c = lin & 63;
    Vt[vbase + (size_t)d * 2048 + c] = vt[c][d];
  }
}

// ---------------- causal flash attention (fold-paired, dbuf, 8 waves) ----------------
__global__ __launch_bounds__(512, 2) void attn_fwd(
    const unsigned short* __restrict__ Q, const unsigned short* __restrict__ K,
    const unsigned short* __restrict__ Vt, unsigned short* __restrict__ AO) {
  const int bid = blockIdx.x;
  const int bh = (bid & 7) * 4 + ((bid >> 3) & 3);  // 4 bh per XCD -> L2 reuse
  const int qp = bid >> 5;                          // 0..7
  const int b = bh >> 4, h = bh & 15;
  __shared__ unsigned short sK[2][64 * 128];
  __shared__ unsigned short sV[2][128 * 64];
  __shared__ unsigned short sP[8][16 * 64];
  const int tid = threadIdx.x, w = tid >> 6, l = tid & 63;
  const int g = l >> 4, lr = l & 15;
  const size_t qkbase = (size_t)bh * 2048 * 128;
  const size_t vbase = (size_t)bh * 128 * 2048;
  const float scale = 0.08838834764831845f;  // 1/sqrt(128)

  auto stage = [&](int buf, int kt) {
#pragma unroll
    for (int j = 0; j < 2; ++j) {
      int r = w * 2 + j;                       // 16 issues of 1KB each
      int kv = r * 4 + (l >> 4);               // sK rows: 4 per issue
      int sc = (l & 15) ^ (kv & 15);
      async_copy16(&sK[buf][r * 512],
                   K + qkbase + (size_t)(kt * 64 + kv) * 128 + sc * 8);
      int d = r * 8 + (l >> 3);                // sV rows: 8 per issue
      int sv = (l & 7) ^ (d & 7);
      async_copy16(&sV[buf][r * 512],
                   Vt + vbase + (size_t)d * 2048 + kt * 64 + sv * 8);
    }
  };

  auto process = [&](int qt) {
    const int q0w = qt * 128 + w * 16;
    bf16x8 qf[4];
#pragma unroll
    for (int kc = 0; kc < 4; ++kc)
      qf[kc] = *(const bf16x8*)(Q + qkbase + (size_t)(q0w + lr) * 128 +
                                kc * 32 + g * 8);
    f32x4 of[8];
    float mrow[4], lsum[4];
#pragma unroll
    for (int nd = 0; nd < 8; ++nd) of[nd] = f32x4{0.f, 0.f, 0.f, 0.f};
#pragma unroll
    for (int jr = 0; jr < 4; ++jr) { mrow[jr] = -1e30f; lsum[jr] = 0.f; }

    const int NT = 2 * qt + 2;
    __syncthreads();                 // prior tile's reads done before restage
    stage(0, 0);
    int cur = 0;
    for (int kt = 0; kt < NT; ++kt) {
      asm volatile("s_waitcnt vmcnt(0)" ::: "memory");
      __syncthreads();
      if (kt + 1 < NT) stage(cur ^ 1, kt + 1);   // prefetch hides under compute

      if (kt * 64 <= q0w + 15) {                 // skip fully-masked waves
        // ---- S = Q K^T ----
        f32x4 sacc[4];
#pragma unroll
        for (int ni = 0; ni < 4; ++ni) sacc[ni] = f32x4{0.f, 0.f, 0.f, 0.f};
#pragma unroll
        for (int kc = 0; kc < 4; ++kc)
#pragma unroll
          for (int ni = 0; ni < 4; ++ni) {
            int kv = ni * 16 + lr;
            bf16x8 kf = *(const bf16x8*)&sK[cur][kv * 128 +
                          (((kc * 4 + g) ^ (kv & 15)) << 3)];
            sacc[ni] = mfma16(qf[kc], kf, sacc[ni]);
          }

        // ---- online softmax (16-lane-group parallel) ----
        const bool needmask = (kt * 64 + 63 > q0w);
        float pm[4] = {-1e30f, -1e30f, -1e30f, -1e30f};
#pragma unroll
        for (int ni = 0; ni < 4; ++ni)
#pragma unroll
          for (int jr = 0; jr < 4; ++jr) {
            float sv = sacc[ni][jr] * scale;
            if (needmask) {
              int kvg = kt * 64 + ni * 16 + lr;
              int qg = q0w + g * 4 + jr;
              if (kvg > qg) sv = -1e30f;
            }
            sacc[ni][jr] = sv;
            pm[jr] = fmaxf(pm[jr], sv);
          }
#pragma unroll
        for (int jr = 0; jr < 4; ++jr) {
          float v = pm[jr];
          v = fmaxf(v, __shfl_xor(v, 1));
          v = fmaxf(v, __shfl_xor(v, 2));
          v = fmaxf(v, __shfl_xor(v, 4));
          v = fmaxf(v, __shfl_xor(v, 8));
          float mnew = fmaxf(mrow[jr], v);
          float fac = __expf(mrow[jr] - mnew);
          mrow[jr] = mnew;
          float rsum = 0.f;
#pragma unroll
          for (int ni = 0; ni < 4; ++ni) {
            float p = __expf(sacc[ni][jr] - mnew);
            sacc[ni][jr] = p;
            rsum += p;
          }
          rsum += __shfl_xor(rsum, 1);
          rsum += __shfl_xor(rsum, 2);
          rsum += __shfl_xor(rsum, 4);
          rsum += __shfl_xor(rsum, 8);
          lsum[jr] = lsum[jr] * fac + rsum;
#pragma unroll
          for (int nd = 0; nd < 8; ++nd) of[nd][jr] *= fac;
        }

        // ---- P -> LDS (bf16, swizzled), wave-private ----
#pragma unroll
        for (int ni = 0; ni < 4; ++ni)
#pragma unroll
          for (int jr = 0; jr < 4; ++jr) {
            int q = g * 4 + jr;
            int kv = ni * 16 + lr;
            sP[w][q * 64 + (((kv >> 3) ^ (q & 7)) << 3) + (kv & 7)] =
                f2bf(sacc[ni][jr]);
          }

        // ---- O += P V ----
#pragma unroll
        for (int kc = 0; kc < 2; ++kc) {
          bf16x8 pa = *(const bf16x8*)&sP[w][lr * 64 +
                        (((kc * 4 + g) ^ (lr & 7)) << 3)];
#pragma unroll
          for (int nd = 0; nd < 8; ++nd) {
            int d = nd * 16 + lr;
            bf16x8 vb = *(const bf16x8*)&sV[cur][d * 64 +
                          (((kc * 4 + g) ^ (d & 7)) << 3)];
            of[nd] = mfma16(pa, vb, of[nd]);
          }
        }
      }
      cur ^= 1;
    }

    // ---- epilogue ----
#pragma unroll
    for (int nd = 0; nd < 8; ++nd)
#pragma unroll
      for (int jr = 0; jr < 4; ++jr) {
        int qrow = q0w + g * 4 + jr;
        int d = nd * 16 + lr;
        AO[(size_t)(b * 2048 + qrow) * 2048 + h * 128 + d] =
            f2bf(of[nd][jr] / lsum[jr]);
      }
  };

  process(qp);
  process(15 - qp);
}

// ---------------- launch ----------------
extern "C" void kernel_launch(void* const* d_in, const int* in_sizes, int n_in,
                              void* d_out, int out_size, void* d_ws, size_t ws_size,
                              hipStream_t stream) {
  (void)in_sizes; (void)n_in; (void)out_size; (void)ws_size;
  const float* x = (const float*)d_in[0];
  const float* wqkv = (const float*)d_in[1];
  const float* wproj = (const float*)d_in[2];

  char* ws = (char*)d_ws;
  unsigned short* WPROJB = (unsigned short*)(ws + 0);            //  8.4 MB
  unsigned short* XB     = (unsigned short*)(ws + 8388608);      // 16.8 MB (reused as AO)
  unsigned short* WQKVB  = (unsigned short*)(ws + 25165824);     // 25.2 MB (reused as Q)
  unsigned short* QKV    = (unsigned short*)(ws + 50331648);     // 50.3 MB
  unsigned short* Kr     = (unsigned short*)(ws + 100663296);    // 16.8 MB
  unsigned short* Vt     = (unsigned short*)(ws + 117440512);    // 16.8 MB
  float2*         CS     = (float2*)(ws + 134217728);            //  1.0 MB
  unsigned short* AO = XB;
  unsigned short* Qr = WQKVB;

  rope_table<<<512, 256, 0, stream>>>(CS);
  cvt_f32_bf16<<<2048, 256, 0, stream>>>(x, XB, 8388608 / 8);
  cvt_f32_bf16<<<2048, 256, 0, stream>>>(wqkv, WQKVB, 12582912 / 8);
  cvt_f32_bf16<<<1024, 256, 0, stream>>>(wproj, WPROJB, 4194304 / 8);
  // qkv = x @ w_qkv^T : [4096,2048] x [6144,2048]^T  (24x32 = 768 blocks, 3 rounds)
  gemm_bt2<false><<<dim3(24, 32), 512, 0, stream>>>(XB, WQKVB, QKV, 4096, 6144, 2048);
  prep_rope<<<dim3(32, 16, 2), 256, 0, stream>>>(QKV, CS, Qr, Kr, Vt);
  attn_fwd<<<256, 512, 0, stream>>>(Qr, Kr, Vt, AO);
  // out = ao @ w_proj^T : [4096,2048] x [2048,2048]^T  (8x32 = 256 blocks, 1 round)
  gemm_bt2<true><<<dim3(8, 32), 512, 0, stream>>>(AO, WPROJB, d_out, 4096, 2048, 2048);
}

// Round 5
// 458.155 us; speedup vs baseline: 1.0131x; 1.0131x over previous
//
#include <hip/hip_runtime.h>
#include <stdint.h>

typedef float f32x4 __attribute__((ext_vector_type(4)));
typedef __bf16 bf16x8 __attribute__((ext_vector_type(8)));
typedef unsigned short u16x8 __attribute__((ext_vector_type(8)));

__device__ __forceinline__ unsigned short f2bf(float f) {
  union { float f; unsigned u; } x; x.f = f;
  unsigned r = x.u + 0x7fffu + ((x.u >> 16) & 1u);
  return (unsigned short)(r >> 16);
}
__device__ __forceinline__ float bf2f(unsigned short u) {
  union { unsigned u; float f; } x; x.u = ((unsigned)u) << 16;
  return x.f;
}
__device__ __forceinline__ void async_copy16(void* lds, const void* g) {
  __builtin_amdgcn_global_load_lds(
      (const unsigned int __attribute__((address_space(1)))*)g,
      (unsigned int __attribute__((address_space(3)))*)lds, 16, 0, 0);
}
__device__ __forceinline__ f32x4 mfma16(bf16x8 a, bf16x8 b, f32x4 c) {
  return __builtin_amdgcn_mfma_f32_16x16x32_bf16(a, b, c, 0, 0, 0);
}

// ---------------- fp32 -> bf16 convert ----------------
__global__ __launch_bounds__(256) void cvt_f32_bf16(
    const float* __restrict__ in, unsigned short* __restrict__ out, int n8) {
  int stride = gridDim.x * blockDim.x;
  for (int i = blockIdx.x * blockDim.x + threadIdx.x; i < n8; i += stride) {
    const float4* p = (const float4*)in + (size_t)i * 2;
    float4 a = p[0], b = p[1];
    u16x8 o;
    o[0] = f2bf(a.x); o[1] = f2bf(a.y); o[2] = f2bf(a.z); o[3] = f2bf(a.w);
    o[4] = f2bf(b.x); o[5] = f2bf(b.y); o[6] = f2bf(b.z); o[7] = f2bf(b.w);
    *((u16x8*)out + i) = o;
  }
}

// ---------------- RoPE cos/sin table ----------------
__global__ __launch_bounds__(256) void rope_table(float2* __restrict__ cs) {
  int idx = blockIdx.x * 256 + threadIdx.x;
  if (idx >= 2048 * 64) return;
  int t = idx >> 6, j = idx & 63;
  float inv = expf(-0.14391156516026f * (float)j);
  float ang = (float)t * inv;
  cs[idx] = make_float2(cosf(ang), sinf(ang));
}

// ---------------- GEMM v3: 8-phase-style deep pipeline ----------------
// C[M,N] = A[M,K]*Bt[N,K]^T. BM x 256 tile, BK=32, 512 thr = 8 waves (2Mx4N).
// Triple-buffered LDS; tile t staged during tile t-2 into buf[t%3]; counted
// vmcnt(L) at tile boundary (L = loads/tile/thread), raw s_barriers only.
// Per tile: 2 phases, each {ds_read frags + stage quarter -> barrier ->
// setprio(1) MFMA cluster setprio(0) -> barrier}.
// Swizzle slot ^= (row&3)^((row>>2)&3): 8-lane groups hit 32 distinct banks.
template <int TBM, bool OUT_F32>
__global__ __launch_bounds__(512, 2) void gemm8p(
    const unsigned short* __restrict__ A, const unsigned short* __restrict__ Bt,
    void* __restrict__ Cout, int M, int N, int K, int ntx) {
  constexpr int MF = TBM / 32;           // A-frags per wave (8 or 4)
  constexpr int AL = TBM / 128;          // A stage loads/thread (2 or 1)
  constexpr int L = AL + 2;              // loads per tile per thread
  __shared__ unsigned short sA[3][TBM * 32];
  __shared__ unsigned short sB[3][256 * 32];
  const int tid = threadIdx.x;
  const int w = tid >> 6, l = tid & 63;
  const int wm = w >> 2, wn = w & 3;
  const int g = l >> 4, lr = l & 15;
  // bijective XCD swizzle (gridDim.x % 8 == 0): chunk of consecutive tiles/XCD
  const int bid = (int)blockIdx.x;
  const int chunk = (int)gridDim.x >> 3;
  const int sid = (bid & 7) * chunk + (bid >> 3);
  const int by = sid / ntx, bx = sid - by * ntx;
  const int m0 = by * TBM, n0 = bx * 256;

  f32x4 acc[MF][4];
#pragma unroll
  for (int i = 0; i < MF; ++i)
#pragma unroll
    for (int j = 0; j < 4; ++j) acc[i][j] = f32x4{0.f, 0.f, 0.f, 0.f};

  auto stageA = [&](int buf, int kt) {
    const int k0 = kt * 32;
#pragma unroll
    for (int i = 0; i < AL; ++i) {
      int u = i * 512 + w * 64 + l;
      int row = u >> 2, s = u & 3;
      int sg = s ^ ((row & 3) ^ ((row >> 2) & 3));
      async_copy16(&sA[buf][(i * 512 + w * 64) * 8],
                   A + (size_t)(m0 + row) * K + k0 + sg * 8);
    }
  };
  auto stageB = [&](int buf, int kt) {
    const int k0 = kt * 32;
#pragma unroll
    for (int i = 0; i < 2; ++i) {
      int u = i * 512 + w * 64 + l;
      int row = u >> 2, s = u & 3;
      int sg = s ^ ((row & 3) ^ ((row >> 2) & 3));
      async_copy16(&sB[buf][(i * 512 + w * 64) * 8],
                   Bt + (size_t)(n0 + row) * K + k0 + sg * 8);
    }
  };

  const int NK = K / 32;
  stageA(0, 0); stageB(0, 0);
  stageA(1, 1); stageB(1, 1);

  for (int kt = 0; kt < NK; ++kt) {
    const int cur = kt % 3;
    const int nxt = (kt + 2) % 3;
    // ---- tile boundary: counted drain (never 0 mid-loop) ----
    if (kt + 1 < NK) {
      if constexpr (L == 4) asm volatile("s_waitcnt vmcnt(4)" ::: "memory");
      else                  asm volatile("s_waitcnt vmcnt(3)" ::: "memory");
    } else {
      asm volatile("s_waitcnt vmcnt(0)" ::: "memory");
    }
    __builtin_amdgcn_s_barrier();

    // ---- phase A: B-frags + low A-frags, stage A-part of tile kt+2 ----
    bf16x8 bq[4];
#pragma unroll
    for (int ni = 0; ni < 4; ++ni) {
      int row = wn * 64 + ni * 16 + lr;
      int sl = g ^ ((row & 3) ^ ((row >> 2) & 3));
      bq[ni] = *(const bf16x8*)&sB[cur][row * 32 + sl * 8];
    }
    bf16x8 afA[MF / 2];
#pragma unroll
    for (int mi = 0; mi < MF / 2; ++mi) {
      int row = wm * (TBM / 2) + mi * 16 + lr;
      int sl = g ^ ((row & 3) ^ ((row >> 2) & 3));
      afA[mi] = *(const bf16x8*)&sA[cur][row * 32 + sl * 8];
    }
    if (kt + 2 < NK) stageA(nxt, kt + 2);
    __builtin_amdgcn_s_barrier();
    __builtin_amdgcn_s_setprio(1);
#pragma unroll
    for (int mi = 0; mi < MF / 2; ++mi)
#pragma unroll
      for (int ni = 0; ni < 4; ++ni)
        acc[mi][ni] = mfma16(afA[mi], bq[ni], acc[mi][ni]);
    __builtin_amdgcn_s_setprio(0);
    __builtin_amdgcn_s_barrier();

    // ---- phase B: high A-frags, stage B-part of tile kt+2 ----
    bf16x8 afB[MF / 2];
#pragma unroll
    for (int mi = 0; mi < MF / 2; ++mi) {
      int row = wm * (TBM / 2) + (MF / 2 + mi) * 16 + lr;
      int sl = g ^ ((row & 3) ^ ((row >> 2) & 3));
      afB[mi] = *(const bf16x8*)&sA[cur][row * 32 + sl * 8];
    }
    if (kt + 2 < NK) stageB(nxt, kt + 2);
    __builtin_amdgcn_s_barrier();
    __builtin_amdgcn_s_setprio(1);
#pragma unroll
    for (int mi = 0; mi < MF / 2; ++mi)
#pragma unroll
      for (int ni = 0; ni < 4; ++ni)
        acc[MF / 2 + mi][ni] = mfma16(afB[mi], bq[ni], acc[MF / 2 + mi][ni]);
    __builtin_amdgcn_s_setprio(0);
    __builtin_amdgcn_s_barrier();
  }

  // ---- epilogue ----
#pragma unroll
  for (int mi = 0; mi < MF; ++mi)
#pragma unroll
    for (int ni = 0; ni < 4; ++ni) {
      int col = n0 + wn * 64 + ni * 16 + lr;
#pragma unroll
      for (int jr = 0; jr < 4; ++jr) {
        int row = m0 + wm * (TBM / 2) + mi * 16 + g * 4 + jr;
        float v = acc[mi][ni][jr];
        if (OUT_F32)
          ((float*)Cout)[(size_t)row * N + col] = v;
        else
          ((unsigned short*)Cout)[(size_t)row * N + col] = f2bf(v);
      }
    }
}

// ---------------- RoPE + scatter ----------------
__global__ __launch_bounds__(256) void prep_rope(
    const unsigned short* __restrict__ qkv, const float2* __restrict__ cs,
    unsigned short* __restrict__ Q, unsigned short* __restrict__ K,
    unsigned short* __restrict__ Vt) {
  const int tt = blockIdx.x, h = blockIdx.y, b = blockIdx.z;
  const int t0 = tt * 64;
  const int tid = threadIdx.x;
  __shared__ unsigned short vt[64][130];

#pragma unroll 4
  for (int i = 0; i < 32; ++i) {
    int lin = i * 256 + tid;
    int r = lin >> 7, j = lin & 127;
    int t = t0 + r;
    int jj = j & 63;
    size_t rowbase = ((size_t)(b * 2048 + t)) * 6144 + h * 128;
    float2 c_s = cs[t * 64 + jj];
    float q1 = bf2f(qkv[rowbase + 2 * jj]);
    float q2 = bf2f(qkv[rowbase + 2 * jj + 1]);
    float k1 = bf2f(qkv[rowbase + 2048 + 2 * jj]);
    float k2 = bf2f(qkv[rowbase + 2048 + 2 * jj + 1]);
    float qo = (j < 64) ? (q1 * c_s.x - q2 * c_s.y) : (q1 * c_s.y + q2 * c_s.x);
    float ko = (j < 64) ? (k1 * c_s.x - k2 * c_s.y) : (k1 * c_s.y + k2 * c_s.x);
    size_t obase = ((size_t)((b * 16 + h) * 2048 + t)) * 128 + j;
    Q[obase] = f2bf(qo);
    K[obase] = f2bf(ko);
    vt[r][j] = qkv[rowbase + 4096 + j];
  }
  __syncthreads();
  size_t vbase = ((size_t)((b * 16 + h) * 128)) * 2048 + t0;
#pragma unroll 4
  for (int i = 0; i < 32; ++i) {
    int lin = i * 256 + tid;
    int d = lin >> 6, c = lin & 63;
    Vt[vbase + (size_t)d * 2048 + c] = vt[c][d];
  }
}

// ---------------- causal flash attention (fold-paired, dbuf, 8 waves) ----------------
__global__ __launch_bounds__(512, 2) void attn_fwd(
    const unsigned short* __restrict__ Q, const unsigned short* __restrict__ K,
    const unsigned short* __restrict__ Vt, unsigned short* __restrict__ AO) {
  const int bid = blockIdx.x;
  const int bh = (bid & 7) * 4 + ((bid >> 3) & 3);
  const int qp = bid >> 5;
  const int b = bh >> 4, h = bh & 15;
  __shared__ unsigned short sK[2][64 * 128];
  __shared__ unsigned short sV[2][128 * 64];
  __shared__ unsigned short sP[8][16 * 64];
  const int tid = threadIdx.x, w = tid >> 6, l = tid & 63;
  const int g = l >> 4, lr = l & 15;
  const size_t qkbase = (size_t)bh * 2048 * 128;
  const size_t vbase = (size_t)bh * 128 * 2048;
  const float scale = 0.08838834764831845f;

  auto stage = [&](int buf, int kt) {
#pragma unroll
    for (int j = 0; j < 2; ++j) {
      int r = w * 2 + j;
      int kv = r * 4 + (l >> 4);
      int sc = (l & 15) ^ (kv & 15);
      async_copy16(&sK[buf][r * 512],
                   K + qkbase + (size_t)(kt * 64 + kv) * 128 + sc * 8);
      int d = r * 8 + (l >> 3);
      int sv = (l & 7) ^ (d & 7);
      async_copy16(&sV[buf][r * 512],
                   Vt + vbase + (size_t)d * 2048 + kt * 64 + sv * 8);
    }
  };

  auto process = [&](int qt) {
    const int q0w = qt * 128 + w * 16;
    bf16x8 qf[4];
#pragma unroll
    for (int kc = 0; kc < 4; ++kc)
      qf[kc] = *(const bf16x8*)(Q + qkbase + (size_t)(q0w + lr) * 128 +
                                kc * 32 + g * 8);
    f32x4 of[8];
    float mrow[4], lsum[4];
#pragma unroll
    for (int nd = 0; nd < 8; ++nd) of[nd] = f32x4{0.f, 0.f, 0.f, 0.f};
#pragma unroll
    for (int jr = 0; jr < 4; ++jr) { mrow[jr] = -1e30f; lsum[jr] = 0.f; }

    const int NT = 2 * qt + 2;
    __syncthreads();
    stage(0, 0);
    int cur = 0;
    for (int kt = 0; kt < NT; ++kt) {
      asm volatile("s_waitcnt vmcnt(0)" ::: "memory");
      __syncthreads();
      if (kt + 1 < NT) stage(cur ^ 1, kt + 1);

      if (kt * 64 <= q0w + 15) {
        f32x4 sacc[4];
#pragma unroll
        for (int ni = 0; ni < 4; ++ni) sacc[ni] = f32x4{0.f, 0.f, 0.f, 0.f};
#pragma unroll
        for (int kc = 0; kc < 4; ++kc)
#pragma unroll
          for (int ni = 0; ni < 4; ++ni) {
            int kv = ni * 16 + lr;
            bf16x8 kf = *(const bf16x8*)&sK[cur][kv * 128 +
                          (((kc * 4 + g) ^ (kv & 15)) << 3)];
            sacc[ni] = mfma16(qf[kc], kf, sacc[ni]);
          }

        const bool needmask = (kt * 64 + 63 > q0w);
        float pm[4] = {-1e30f, -1e30f, -1e30f, -1e30f};
#pragma unroll
        for (int ni = 0; ni < 4; ++ni)
#pragma unroll
          for (int jr = 0; jr < 4; ++jr) {
            float sv = sacc[ni][jr] * scale;
            if (needmask) {
              int kvg = kt * 64 + ni * 16 + lr;
              int qg = q0w + g * 4 + jr;
              if (kvg > qg) sv = -1e30f;
            }
            sacc[ni][jr] = sv;
            pm[jr] = fmaxf(pm[jr], sv);
          }
#pragma unroll
        for (int jr = 0; jr < 4; ++jr) {
          float v = pm[jr];
          v = fmaxf(v, __shfl_xor(v, 1));
          v = fmaxf(v, __shfl_xor(v, 2));
          v = fmaxf(v, __shfl_xor(v, 4));
          v = fmaxf(v, __shfl_xor(v, 8));
          float mnew = fmaxf(mrow[jr], v);
          float fac = __expf(mrow[jr] - mnew);
          mrow[jr] = mnew;
          float rsum = 0.f;
#pragma unroll
          for (int ni = 0; ni < 4; ++ni) {
            float p = __expf(sacc[ni][jr] - mnew);
            sacc[ni][jr] = p;
            rsum += p;
          }
          rsum += __shfl_xor(rsum, 1);
          rsum += __shfl_xor(rsum, 2);
          rsum += __shfl_xor(rsum, 4);
          rsum += __shfl_xor(rsum, 8);
          lsum[jr] = lsum[jr] * fac + rsum;
#pragma unroll
          for (int nd = 0; nd < 8; ++nd) of[nd][jr] *= fac;
        }

#pragma unroll
        for (int ni = 0; ni < 4; ++ni)
#pragma unroll
          for (int jr = 0; jr < 4; ++jr) {
            int q = g * 4 + jr;
            int kv = ni * 16 + lr;
            sP[w][q * 64 + (((kv >> 3) ^ (q & 7)) << 3) + (kv & 7)] =
                f2bf(sacc[ni][jr]);
          }

#pragma unroll
        for (int kc = 0; kc < 2; ++kc) {
          bf16x8 pa = *(const bf16x8*)&sP[w][lr * 64 +
                        (((kc * 4 + g) ^ (lr & 7)) << 3)];
#pragma unroll
          for (int nd = 0; nd < 8; ++nd) {
            int d = nd * 16 + lr;
            bf16x8 vb = *(const bf16x8*)&sV[cur][d * 64 +
                          (((kc * 4 + g) ^ (d & 7)) << 3)];
            of[nd] = mfma16(pa, vb, of[nd]);
          }
        }
      }
      cur ^= 1;
    }

#pragma unroll
    for (int nd = 0; nd < 8; ++nd)
#pragma unroll
      for (int jr = 0; jr < 4; ++jr) {
        int qrow = q0w + g * 4 + jr;
        int d = nd * 16 + lr;
        AO[(size_t)(b * 2048 + qrow) * 2048 + h * 128 + d] =
            f2bf(of[nd][jr] / lsum[jr]);
      }
  };

  process(qp);
  process(15 - qp);
}

// ---------------- launch ----------------
extern "C" void kernel_launch(void* const* d_in, const int* in_sizes, int n_in,
                              void* d_out, int out_size, void* d_ws, size_t ws_size,
                              hipStream_t stream) {
  (void)in_sizes; (void)n_in; (void)out_size; (void)ws_size;
  const float* x = (const float*)d_in[0];
  const float* wqkv = (const float*)d_in[1];
  const float* wproj = (const float*)d_in[2];

  char* ws = (char*)d_ws;
  unsigned short* WPROJB = (unsigned short*)(ws + 0);            //  8.4 MB
  unsigned short* XB     = (unsigned short*)(ws + 8388608);      // 16.8 MB (reused as AO)
  unsigned short* WQKVB  = (unsigned short*)(ws + 25165824);     // 25.2 MB (reused as Q)
  unsigned short* QKV    = (unsigned short*)(ws + 50331648);     // 50.3 MB
  unsigned short* Kr     = (unsigned short*)(ws + 100663296);    // 16.8 MB
  unsigned short* Vt     = (unsigned short*)(ws + 117440512);    // 16.8 MB
  float2*         CS     = (float2*)(ws + 134217728);            //  1.0 MB
  unsigned short* AO = XB;
  unsigned short* Qr = WQKVB;

  rope_table<<<512, 256, 0, stream>>>(CS);
  cvt_f32_bf16<<<2048, 256, 0, stream>>>(x, XB, 8388608 / 8);
  cvt_f32_bf16<<<2048, 256, 0, stream>>>(wqkv, WQKVB, 12582912 / 8);
  cvt_f32_bf16<<<1024, 256, 0, stream>>>(wproj, WPROJB, 4194304 / 8);
  // qkv = x @ w_qkv^T : [4096,2048] x [6144,2048]^T   (16x24 tiles = 384 blocks)
  gemm8p<256, false><<<384, 512, 0, stream>>>(XB, WQKVB, QKV, 4096, 6144, 2048, 24);
  prep_rope<<<dim3(32, 16, 2), 256, 0, stream>>>(QKV, CS, Qr, Kr, Vt);
  attn_fwd<<<256, 512, 0, stream>>>(Qr, Kr, Vt, AO);
  // out = ao @ w_proj^T : [4096,2048] x [2048,2048]^T (32x8 tiles = 256 blocks)
  gemm8p<128, true><<<256, 512, 0, stream>>>(AO, WPROJB, d_out, 4096, 2048, 2048, 8);
}

// Round 6
// 423.639 us; speedup vs baseline: 1.0956x; 1.0815x over previous
//
#include <hip/hip_runtime.h>
#include <stdint.h>

typedef float f32x4 __attribute__((ext_vector_type(4)));
typedef __bf16 bf16x8 __attribute__((ext_vector_type(8)));
typedef unsigned short u16x8 __attribute__((ext_vector_type(8)));

__device__ __forceinline__ unsigned short f2bf(float f) {
  union { float f; unsigned u; } x; x.f = f;
  unsigned r = x.u + 0x7fffu + ((x.u >> 16) & 1u);
  return (unsigned short)(r >> 16);
}
__device__ __forceinline__ float bf2f(unsigned short u) {
  union { unsigned u; float f; } x; x.u = ((unsigned)u) << 16;
  return x.f;
}
__device__ __forceinline__ void async_copy16(void* lds, const void* g) {
  __builtin_amdgcn_global_load_lds(
      (const unsigned int __attribute__((address_space(1)))*)g,
      (unsigned int __attribute__((address_space(3)))*)lds, 16, 0, 0);
}
__device__ __forceinline__ f32x4 mfma16(bf16x8 a, bf16x8 b, f32x4 c) {
  return __builtin_amdgcn_mfma_f32_16x16x32_bf16(a, b, c, 0, 0, 0);
}

// ---------------- fp32 -> bf16 convert ----------------
__global__ __launch_bounds__(256) void cvt_f32_bf16(
    const float* __restrict__ in, unsigned short* __restrict__ out, int n8) {
  int stride = gridDim.x * blockDim.x;
  for (int i = blockIdx.x * blockDim.x + threadIdx.x; i < n8; i += stride) {
    const float4* p = (const float4*)in + (size_t)i * 2;
    float4 a = p[0], b = p[1];
    u16x8 o;
    o[0] = f2bf(a.x); o[1] = f2bf(a.y); o[2] = f2bf(a.z); o[3] = f2bf(a.w);
    o[4] = f2bf(b.x); o[5] = f2bf(b.y); o[6] = f2bf(b.z); o[7] = f2bf(b.w);
    *((u16x8*)out + i) = o;
  }
}

// ---------------- RoPE cos/sin table ----------------
__global__ __launch_bounds__(256) void rope_table(float2* __restrict__ cs) {
  int idx = blockIdx.x * 256 + threadIdx.x;
  if (idx >= 2048 * 64) return;
  int t = idx >> 6, j = idx & 63;
  float inv = expf(-0.14391156516026f * (float)j);
  float ang = (float)t * inv;
  cs[idx] = make_float2(cosf(ang), sinf(ang));
}

// ---------------- GEMM v4: deep pipeline, exact-round tiling ----------------
// C[M,N] = A[M,K]*Bt[N,K]^T. BM=128, BN=256, BK=64; 512 thr = 8 waves (2Mx4N),
// per-wave 64x64. TRIPLE-buffered LDS (144 KB): tile t staged during t-2 into
// buf[t%3]; boundary wait vmcnt(6) (tile t+1's 6 loads stay in flight; never 0
// mid-loop). 2 phases/tile: {ds_read frags + gloads -> s_barrier -> setprio(1)
// 16 MFMA setprio(0)}. Rows are 128 B (8x16B slots); swizzle slot ^= row&7 at
// stage-source and ds_read (uniform 8 lanes/bank-quad).
template <bool OUT_F32>
__global__ __launch_bounds__(512, 2) void gemm_dp(
    const unsigned short* __restrict__ A, const unsigned short* __restrict__ Bt,
    void* __restrict__ Cout, int M, int N, int K) {
  __shared__ unsigned short sA[3][128 * 64];   // 48 KB
  __shared__ unsigned short sB[3][256 * 64];   // 96 KB
  const int tid = threadIdx.x;
  const int w = tid >> 6, l = tid & 63;
  const int wm = w >> 2, wn = w & 3;
  const int g = l >> 4, lr = l & 15;
  const int m0 = blockIdx.y * 128, n0 = blockIdx.x * 256;

  f32x4 acc[4][4];
#pragma unroll
  for (int i = 0; i < 4; ++i)
#pragma unroll
    for (int j = 0; j < 4; ++j) acc[i][j] = f32x4{0.f, 0.f, 0.f, 0.f};

  auto stageA = [&](int buf, int kt) {     // 2 issues: 16 KB
    const int k0 = kt * 64;
#pragma unroll
    for (int i = 0; i < 2; ++i) {
      int u = i * 512 + tid;
      int row = u >> 3, sl = u & 7;
      int sg = sl ^ (row & 7);
      async_copy16(&sA[buf][u * 8], A + (size_t)(m0 + row) * K + k0 + sg * 8);
    }
  };
  auto stageB = [&](int buf, int kt, int half) {  // 2 issues per half: 16 KB
    const int k0 = kt * 64;
#pragma unroll
    for (int i = 0; i < 2; ++i) {
      int u = (half * 2 + i) * 512 + tid;
      int row = u >> 3, sl = u & 7;
      int sg = sl ^ (row & 7);
      async_copy16(&sB[buf][u * 8], Bt + (size_t)(n0 + row) * K + k0 + sg * 8);
    }
  };

  const int NK = K / 64;
  stageA(0, 0); stageB(0, 0, 0); stageB(0, 0, 1);
  stageA(1, 1); stageB(1, 1, 0); stageB(1, 1, 1);

  for (int kt = 0; kt < NK; ++kt) {
    const int cur = kt % 3, nxt = (kt + 2) % 3;
    // boundary: tile kt landed iff <=6 outstanding (tile kt+1's stay in flight)
    if (kt + 1 < NK) asm volatile("s_waitcnt vmcnt(6)" ::: "memory");
    else             asm volatile("s_waitcnt vmcnt(0)" ::: "memory");
    __builtin_amdgcn_s_barrier();

    // ---- phase 0: B-frags + A-frags(mi 0,1); stage A + B-half0 of kt+2 ----
    bf16x8 bq[4][2], af0[2][2];
#pragma unroll
    for (int ni = 0; ni < 4; ++ni) {
      int row = wn * 64 + ni * 16 + lr;
#pragma unroll
      for (int kk = 0; kk < 2; ++kk)
        bq[ni][kk] = *(const bf16x8*)&sB[cur][row * 64 +
                       (((kk * 4 + g) ^ (row & 7)) << 3)];
    }
#pragma unroll
    for (int mi = 0; mi < 2; ++mi) {
      int row = wm * 64 + mi * 16 + lr;
#pragma unroll
      for (int kk = 0; kk < 2; ++kk)
        af0[mi][kk] = *(const bf16x8*)&sA[cur][row * 64 +
                        (((kk * 4 + g) ^ (row & 7)) << 3)];
    }
    if (kt + 2 < NK) { stageA(nxt, kt + 2); stageB(nxt, kt + 2, 0); }
    __builtin_amdgcn_s_barrier();
    __builtin_amdgcn_s_setprio(1);
#pragma unroll
    for (int kk = 0; kk < 2; ++kk)
#pragma unroll
      for (int mi = 0; mi < 2; ++mi)
#pragma unroll
        for (int ni = 0; ni < 4; ++ni)
          acc[mi][ni] = mfma16(af0[mi][kk], bq[ni][kk], acc[mi][ni]);
    __builtin_amdgcn_s_setprio(0);

    // ---- phase 1: A-frags(mi 2,3); stage B-half1 of kt+2 ----
    bf16x8 af1[2][2];
#pragma unroll
    for (int mi = 0; mi < 2; ++mi) {
      int row = wm * 64 + (2 + mi) * 16 + lr;
#pragma unroll
      for (int kk = 0; kk < 2; ++kk)
        af1[mi][kk] = *(const bf16x8*)&sA[cur][row * 64 +
                        (((kk * 4 + g) ^ (row & 7)) << 3)];
    }
    if (kt + 2 < NK) stageB(nxt, kt + 2, 1);
    __builtin_amdgcn_s_barrier();
    __builtin_amdgcn_s_setprio(1);
#pragma unroll
    for (int kk = 0; kk < 2; ++kk)
#pragma unroll
      for (int mi = 0; mi < 2; ++mi)
#pragma unroll
        for (int ni = 0; ni < 4; ++ni)
          acc[2 + mi][ni] = mfma16(af1[mi][kk], bq[ni][kk], acc[2 + mi][ni]);
    __builtin_amdgcn_s_setprio(0);
  }

  // ---- epilogue ----
#pragma unroll
  for (int mi = 0; mi < 4; ++mi)
#pragma unroll
    for (int ni = 0; ni < 4; ++ni) {
      int col = n0 + wn * 64 + ni * 16 + lr;
#pragma unroll
      for (int jr = 0; jr < 4; ++jr) {
        int row = m0 + wm * 64 + mi * 16 + g * 4 + jr;
        float v = acc[mi][ni][jr];
        if (OUT_F32)
          ((float*)Cout)[(size_t)row * N + col] = v;
        else
          ((unsigned short*)Cout)[(size_t)row * N + col] = f2bf(v);
      }
    }
}

// ---------------- RoPE + scatter ----------------
__global__ __launch_bounds__(256) void prep_rope(
    const unsigned short* __restrict__ qkv, const float2* __restrict__ cs,
    unsigned short* __restrict__ Q, unsigned short* __restrict__ K,
    unsigned short* __restrict__ Vt) {
  const int tt = blockIdx.x, h = blockIdx.y, b = blockIdx.z;
  const int t0 = tt * 64;
  const int tid = threadIdx.x;
  __shared__ unsigned short vt[64][130];

#pragma unroll 4
  for (int i = 0; i < 32; ++i) {
    int lin = i * 256 + tid;
    int r = lin >> 7, j = lin & 127;
    int t = t0 + r;
    int jj = j & 63;
    size_t rowbase = ((size_t)(b * 2048 + t)) * 6144 + h * 128;
    float2 c_s = cs[t * 64 + jj];
    float q1 = bf2f(qkv[rowbase + 2 * jj]);
    float q2 = bf2f(qkv[rowbase + 2 * jj + 1]);
    float k1 = bf2f(qkv[rowbase + 2048 + 2 * jj]);
    float k2 = bf2f(qkv[rowbase + 2048 + 2 * jj + 1]);
    float qo = (j < 64) ? (q1 * c_s.x - q2 * c_s.y) : (q1 * c_s.y + q2 * c_s.x);
    float ko = (j < 64) ? (k1 * c_s.x - k2 * c_s.y) : (k1 * c_s.y + k2 * c_s.x);
    size_t obase = ((size_t)((b * 16 + h) * 2048 + t)) * 128 + j;
    Q[obase] = f2bf(qo);
    K[obase] = f2bf(ko);
    vt[r][j] = qkv[rowbase + 4096 + j];
  }
  __syncthreads();
  size_t vbase = ((size_t)((b * 16 + h) * 128)) * 2048 + t0;
#pragma unroll 4
  for (int i = 0; i < 32; ++i) {
    int lin = i * 256 + tid;
    int d = lin >> 6, c = lin & 63;
    Vt[vbase + (size_t)d * 2048 + c] = vt[c][d];
  }
}

// ---------------- causal flash attention (fold-paired, dbuf, 8 waves) ----------------
__global__ __launch_bounds__(512, 2) void attn_fwd(
    const unsigned short* __restrict__ Q, const unsigned short* __restrict__ K,
    const unsigned short* __restrict__ Vt, unsigned short* __restrict__ AO) {
  const int bid = blockIdx.x;
  const int bh = (bid & 7) * 4 + ((bid >> 3) & 3);
  const int qp = bid >> 5;
  const int b = bh >> 4, h = bh & 15;
  __shared__ unsigned short sK[2][64 * 128];
  __shared__ unsigned short sV[2][128 * 64];
  __shared__ unsigned short sP[8][16 * 64];
  const int tid = threadIdx.x, w = tid >> 6, l = tid & 63;
  const int g = l >> 4, lr = l & 15;
  const size_t qkbase = (size_t)bh * 2048 * 128;
  const size_t vbase = (size_t)bh * 128 * 2048;
  const float scale = 0.08838834764831845f;

  auto stage = [&](int buf, int kt) {
#pragma unroll
    for (int j = 0; j < 2; ++j) {
      int r = w * 2 + j;
      int kv = r * 4 + (l >> 4);
      int sc = (l & 15) ^ (kv & 15);
      async_copy16(&sK[buf][r * 512],
                   K + qkbase + (size_t)(kt * 64 + kv) * 128 + sc * 8);
      int d = r * 8 + (l >> 3);
      int sv = (l & 7) ^ (d & 7);
      async_copy16(&sV[buf][r * 512],
                   Vt + vbase + (size_t)d * 2048 + kt * 64 + sv * 8);
    }
  };

  auto process = [&](int qt) {
    const int q0w = qt * 128 + w * 16;
    bf16x8 qf[4];
#pragma unroll
    for (int kc = 0; kc < 4; ++kc)
      qf[kc] = *(const bf16x8*)(Q + qkbase + (size_t)(q0w + lr) * 128 +
                                kc * 32 + g * 8);
    f32x4 of[8];
    float mrow[4], lsum[4];
#pragma unroll
    for (int nd = 0; nd < 8; ++nd) of[nd] = f32x4{0.f, 0.f, 0.f, 0.f};
#pragma unroll
    for (int jr = 0; jr < 4; ++jr) { mrow[jr] = -1e30f; lsum[jr] = 0.f; }

    const int NT = 2 * qt + 2;
    __syncthreads();
    stage(0, 0);
    int cur = 0;
    for (int kt = 0; kt < NT; ++kt) {
      asm volatile("s_waitcnt vmcnt(0)" ::: "memory");
      __syncthreads();
      if (kt + 1 < NT) stage(cur ^ 1, kt + 1);

      if (kt * 64 <= q0w + 15) {
        f32x4 sacc[4];
#pragma unroll
        for (int ni = 0; ni < 4; ++ni) sacc[ni] = f32x4{0.f, 0.f, 0.f, 0.f};
#pragma unroll
        for (int kc = 0; kc < 4; ++kc)
#pragma unroll
          for (int ni = 0; ni < 4; ++ni) {
            int kv = ni * 16 + lr;
            bf16x8 kf = *(const bf16x8*)&sK[cur][kv * 128 +
                          (((kc * 4 + g) ^ (kv & 15)) << 3)];
            sacc[ni] = mfma16(qf[kc], kf, sacc[ni]);
          }

        const bool needmask = (kt * 64 + 63 > q0w);
        float pm[4] = {-1e30f, -1e30f, -1e30f, -1e30f};
#pragma unroll
        for (int ni = 0; ni < 4; ++ni)
#pragma unroll
          for (int jr = 0; jr < 4; ++jr) {
            float sv = sacc[ni][jr] * scale;
            if (needmask) {
              int kvg = kt * 64 + ni * 16 + lr;
              int qg = q0w + g * 4 + jr;
              if (kvg > qg) sv = -1e30f;
            }
            sacc[ni][jr] = sv;
            pm[jr] = fmaxf(pm[jr], sv);
          }
#pragma unroll
        for (int jr = 0; jr < 4; ++jr) {
          float v = pm[jr];
          v = fmaxf(v, __shfl_xor(v, 1));
          v = fmaxf(v, __shfl_xor(v, 2));
          v = fmaxf(v, __shfl_xor(v, 4));
          v = fmaxf(v, __shfl_xor(v, 8));
          float mnew = fmaxf(mrow[jr], v);
          float fac = __expf(mrow[jr] - mnew);
          mrow[jr] = mnew;
          float rsum = 0.f;
#pragma unroll
          for (int ni = 0; ni < 4; ++ni) {
            float p = __expf(sacc[ni][jr] - mnew);
            sacc[ni][jr] = p;
            rsum += p;
          }
          rsum += __shfl_xor(rsum, 1);
          rsum += __shfl_xor(rsum, 2);
          rsum += __shfl_xor(rsum, 4);
          rsum += __shfl_xor(rsum, 8);
          lsum[jr] = lsum[jr] * fac + rsum;
#pragma unroll
          for (int nd = 0; nd < 8; ++nd) of[nd][jr] *= fac;
        }

#pragma unroll
        for (int ni = 0; ni < 4; ++ni)
#pragma unroll
          for (int jr = 0; jr < 4; ++jr) {
            int q = g * 4 + jr;
            int kv = ni * 16 + lr;
            sP[w][q * 64 + (((kv >> 3) ^ (q & 7)) << 3) + (kv & 7)] =
                f2bf(sacc[ni][jr]);
          }

#pragma unroll
        for (int kc = 0; kc < 2; ++kc) {
          bf16x8 pa = *(const bf16x8*)&sP[w][lr * 64 +
                        (((kc * 4 + g) ^ (lr & 7)) << 3)];
#pragma unroll
          for (int nd = 0; nd < 8; ++nd) {
            int d = nd * 16 + lr;
            bf16x8 vb = *(const bf16x8*)&sV[cur][d * 64 +
                          (((kc * 4 + g) ^ (d & 7)) << 3)];
            of[nd] = mfma16(pa, vb, of[nd]);
          }
        }
      }
      cur ^= 1;
    }

#pragma unroll
    for (int nd = 0; nd < 8; ++nd)
#pragma unroll
      for (int jr = 0; jr < 4; ++jr) {
        int qrow = q0w + g * 4 + jr;
        int d = nd * 16 + lr;
        AO[(size_t)(b * 2048 + qrow) * 2048 + h * 128 + d] =
            f2bf(of[nd][jr] / lsum[jr]);
      }
  };

  process(qp);
  process(15 - qp);
}

// ---------------- launch ----------------
extern "C" void kernel_launch(void* const* d_in, const int* in_sizes, int n_in,
                              void* d_out, int out_size, void* d_ws, size_t ws_size,
                              hipStream_t stream) {
  (void)in_sizes; (void)n_in; (void)out_size; (void)ws_size;
  const float* x = (const float*)d_in[0];
  const float* wqkv = (const float*)d_in[1];
  const float* wproj = (const float*)d_in[2];

  char* ws = (char*)d_ws;
  unsigned short* WPROJB = (unsigned short*)(ws + 0);            //  8.4 MB
  unsigned short* XB     = (unsigned short*)(ws + 8388608);      // 16.8 MB (reused as AO)
  unsigned short* WQKVB  = (unsigned short*)(ws + 25165824);     // 25.2 MB (reused as Q)
  unsigned short* QKV    = (unsigned short*)(ws + 50331648);     // 50.3 MB
  unsigned short* Kr     = (unsigned short*)(ws + 100663296);    // 16.8 MB
  unsigned short* Vt     = (unsigned short*)(ws + 117440512);    // 16.8 MB
  float2*         CS     = (float2*)(ws + 134217728);            //  1.0 MB
  unsigned short* AO = XB;
  unsigned short* Qr = WQKVB;

  rope_table<<<512, 256, 0, stream>>>(CS);
  cvt_f32_bf16<<<2048, 256, 0, stream>>>(x, XB, 8388608 / 8);
  cvt_f32_bf16<<<2048, 256, 0, stream>>>(wqkv, WQKVB, 12582912 / 8);
  cvt_f32_bf16<<<1024, 256, 0, stream>>>(wproj, WPROJB, 4194304 / 8);
  // qkv = x @ w_qkv^T : [4096,2048] x [6144,2048]^T  (24x32 = 768 blocks, 3 exact rounds)
  gemm_dp<false><<<dim3(24, 32), 512, 0, stream>>>(XB, WQKVB, QKV, 4096, 6144, 2048);
  prep_rope<<<dim3(32, 16, 2), 256, 0, stream>>>(QKV, CS, Qr, Kr, Vt);
  attn_fwd<<<256, 512, 0, stream>>>(Qr, Kr, Vt, AO);
  // out = ao @ w_proj^T : [4096,2048] x [2048,2048]^T (8x32 = 256 blocks, 1 exact round)
  gemm_dp<true><<<dim3(8, 32), 512, 0, stream>>>(AO, WPROJB, d_out, 4096, 2048, 2048);
}